// Round 2
// baseline (1150.564 us; speedup 1.0000x reference)
//
#include <hip/hip_runtime.h>
#include <cmath>

#define NN 50000      // nodes
#define EE 400000     // raw edges
#define ET 450000     // edges + self loops
#define FF 64         // input feature dim
#define HIDD 256
#define KIN 192       // 3*FF
#define LN_EPSF 1e-5f

// ---------------- CSR build ----------------
__global__ void k_degree(const int* __restrict__ ei, int* __restrict__ deg){
  int i = blockIdx.x*blockDim.x + threadIdx.x;
  if (i >= ET) return;
  int d = (i < EE) ? ei[EE + i] : (i - EE);
  atomicAdd(&deg[d], 1);
}

__global__ void k_scan1(const int* __restrict__ deg, int* __restrict__ row_off, int* __restrict__ part){
  __shared__ int s[256];
  int n = blockIdx.x*256 + threadIdx.x;
  int v = (n < NN) ? deg[n] : 0;
  s[threadIdx.x] = v;
  __syncthreads();
  for (int off=1; off<256; off<<=1){
    int t = (threadIdx.x >= off) ? s[threadIdx.x - off] : 0;
    __syncthreads();
    s[threadIdx.x] += t;
    __syncthreads();
  }
  if (n < NN) row_off[n] = s[threadIdx.x] - v;   // exclusive within block
  if (threadIdx.x == 255) part[blockIdx.x] = s[255];
}

__global__ void k_scan2(int* __restrict__ part, int nparts){
  __shared__ int s[256];
  int v = (threadIdx.x < nparts) ? part[threadIdx.x] : 0;
  s[threadIdx.x] = v;
  __syncthreads();
  for (int off=1; off<256; off<<=1){
    int t = (threadIdx.x >= off) ? s[threadIdx.x - off] : 0;
    __syncthreads();
    s[threadIdx.x] += t;
    __syncthreads();
  }
  if (threadIdx.x < nparts) part[threadIdx.x] = s[threadIdx.x] - v;  // exclusive
}

__global__ void k_scan3(int* __restrict__ row_off, const int* __restrict__ part){
  int n = blockIdx.x*256 + threadIdx.x;
  if (n < NN) row_off[n] += part[blockIdx.x];
}

__global__ void k_scatter(const int* __restrict__ ei, const int* __restrict__ row_off,
                          int* __restrict__ cur, int* __restrict__ csr_src){
  int i = blockIdx.x*blockDim.x + threadIdx.x;
  if (i >= ET) return;
  int s, d;
  if (i < EE){ s = ei[i]; d = ei[EE + i]; } else { s = i - EE; d = i - EE; }
  int pos = row_off[d] + atomicAdd(&cur[d], 1);
  csr_src[pos] = s;
}

// ---------------- posenc (f32, matches ref's f32 rounding to ~1e-3) ----------------
__global__ void k_posenc(float* __restrict__ pe){
  int idx = blockIdx.x*blockDim.x + threadIdx.x;
  if (idx >= NN*FF) return;
  int n = idx >> 6, i = idx & 63;
  // rate = 10000^(-2*floor(i/2)/64)
  float rate = exp2f(-(float)(2*(i>>1)) * (1.0f/64.0f) * 13.287712379549449f); // log2(10000)
  float ang = (float)n * rate;
  float s, c;
  sincosf(ang, &s, &c);
  pe[idx] = (i & 1) ? c : s;
}

// ---------------- tiled SIMT GEMM: C[M,256] = A[M,K] @ W[K,256]  (fp32) ----------------
__global__ __launch_bounds__(256) void k_gemm_layer(
    const float* __restrict__ A, const float* __restrict__ W,
    float* __restrict__ C, int M, int K)
{
  __shared__ float As[16][64];
  __shared__ float Bs[16][64];
  int tid = threadIdx.x;
  int tx = tid & 15, ty = tid >> 4;
  int row0 = blockIdx.x*64, col0 = blockIdx.y*64;
  int am = tid >> 2, ak = (tid & 3)*4;
  int bn = (tid & 15)*4, bk = tid >> 4;
  float acc[4][4] = {};
  for (int k0 = 0; k0 < K; k0 += 16){
    int arow = row0 + am;
    float4 av = make_float4(0.f,0.f,0.f,0.f);
    if (arow < M) av = *(const float4*)(A + (size_t)arow*K + k0 + ak);
    As[ak+0][am]=av.x; As[ak+1][am]=av.y; As[ak+2][am]=av.z; As[ak+3][am]=av.w;
    {
      float4 bv = *(const float4*)(W + (size_t)(k0+bk)*HIDD + col0 + bn);
      Bs[bk][bn+0]=bv.x; Bs[bk][bn+1]=bv.y; Bs[bk][bn+2]=bv.z; Bs[bk][bn+3]=bv.w;
    }
    __syncthreads();
    #pragma unroll
    for (int kk=0; kk<16; ++kk){
      float a[4], b[4];
      #pragma unroll
      for (int i=0;i<4;++i) a[i] = As[kk][ty*4+i];
      #pragma unroll
      for (int j=0;j<4;++j) b[j] = Bs[kk][tx*4+j];
      #pragma unroll
      for (int i=0;i<4;++i)
        #pragma unroll
        for (int j=0;j<4;++j)
          acc[i][j] += a[i]*b[j];
    }
    __syncthreads();
  }
  #pragma unroll
  for (int i=0;i<4;++i){
    int r = row0 + ty*4 + i;
    if (r < M){
      int c = col0 + tx*4;
      float4 o = make_float4(acc[i][0], acc[i][1], acc[i][2], acc[i][3]);
      *(float4*)(C + (size_t)r*HIDD + c) = o;
    }
  }
}

// ---------------- input projection GEMM: feats = [x | remb[rid] | posenc] generated on the fly ----------------
__global__ __launch_bounds__(256) void k_gemm_inproj(
    const float* __restrict__ x, const float* __restrict__ remb, const int* __restrict__ rid,
    const float* __restrict__ pe, const float* __restrict__ W, const float* __restrict__ bias,
    float* __restrict__ C)
{
  __shared__ float As[16][64];
  __shared__ float Bs[16][64];
  const int M = NN, K = KIN;
  int tid = threadIdx.x;
  int tx = tid & 15, ty = tid >> 4;
  int row0 = blockIdx.x*64, col0 = blockIdx.y*64;
  int am = tid >> 2, ak = (tid & 3)*4;
  int bn = (tid & 15)*4, bk = tid >> 4;
  float acc[4][4] = {};
  for (int k0 = 0; k0 < K; k0 += 16){
    int arow = row0 + am;
    int kg = k0 + ak;
    float4 av = make_float4(0.f,0.f,0.f,0.f);
    if (arow < M){
      if (kg < 64){
        av = *(const float4*)(x + (size_t)arow*64 + kg);
      } else if (kg < 128){
        int r = rid[arow];
        av = *(const float4*)(remb + (size_t)r*64 + (kg-64));
      } else {
        av = *(const float4*)(pe + (size_t)arow*64 + (kg-128));
      }
    }
    As[ak+0][am]=av.x; As[ak+1][am]=av.y; As[ak+2][am]=av.z; As[ak+3][am]=av.w;
    {
      float4 bv = *(const float4*)(W + (size_t)(k0+bk)*HIDD + col0 + bn);
      Bs[bk][bn+0]=bv.x; Bs[bk][bn+1]=bv.y; Bs[bk][bn+2]=bv.z; Bs[bk][bn+3]=bv.w;
    }
    __syncthreads();
    #pragma unroll
    for (int kk=0; kk<16; ++kk){
      float a[4], b[4];
      #pragma unroll
      for (int i=0;i<4;++i) a[i] = As[kk][ty*4+i];
      #pragma unroll
      for (int j=0;j<4;++j) b[j] = Bs[kk][tx*4+j];
      #pragma unroll
      for (int i=0;i<4;++i)
        #pragma unroll
        for (int j=0;j<4;++j)
          acc[i][j] += a[i]*b[j];
    }
    __syncthreads();
  }
  #pragma unroll
  for (int i=0;i<4;++i){
    int r = row0 + ty*4 + i;
    if (r < M){
      int c = col0 + tx*4;
      float4 o = make_float4(acc[i][0]+bias[c+0], acc[i][1]+bias[c+1],
                             acc[i][2]+bias[c+2], acc[i][3]+bias[c+3]);
      *(float4*)(C + (size_t)r*HIDD + c) = o;
    }
  }
}

// ---------------- per-node attention scores (wave per node) ----------------
__global__ __launch_bounds__(256) void k_scores(
    const float* __restrict__ h2, const float* __restrict__ asrc, const float* __restrict__ adst,
    float* __restrict__ ssrc, float* __restrict__ sdst)
{
  int wv = (blockIdx.x*blockDim.x + threadIdx.x) >> 6;
  if (wv >= NN) return;
  int lane = threadIdx.x & 63;
  int c0 = lane*4;
  float4 hv = *(const float4*)(h2 + (size_t)wv*HIDD + c0);
  float4 av = *(const float4*)(asrc + c0);
  float4 dv = *(const float4*)(adst + c0);
  float ps = hv.x*av.x + hv.y*av.y + hv.z*av.z + hv.w*av.w;
  float pd = hv.x*dv.x + hv.y*dv.y + hv.z*dv.z + hv.w*dv.w;
  #pragma unroll
  for (int o=1;o<16;o<<=1){ ps += __shfl_xor(ps,o); pd += __shfl_xor(pd,o); }
  if ((lane & 15) == 0){
    int head = lane >> 4;
    ssrc[wv*4+head] = ps;
    sdst[wv*4+head] = pd;
  }
}

// ---------------- fused GAT aggregate + bias + relu + layernorm (wave per dst node) ----------------
__global__ __launch_bounds__(256) void k_aggregate(
    const float* __restrict__ h2, const float* __restrict__ ssrc, const float* __restrict__ sdst,
    const int* __restrict__ row_off, const int* __restrict__ deg, const int* __restrict__ csr_src,
    const float* __restrict__ bias, const float* __restrict__ g, const float* __restrict__ bb,
    float* __restrict__ hout)
{
  int n = (blockIdx.x*blockDim.x + threadIdx.x) >> 6;
  if (n >= NN) return;
  int lane = threadIdx.x & 63;
  int head = lane >> 4;
  float sdh = sdst[n*4 + head];
  int ro = row_off[n];
  int dg = deg[n];
  // pass 1: segment max of leaky_relu scores (per head)
  float m = -1e30f;
  for (int j=0;j<dg;++j){
    int s = csr_src[ro+j];
    float e = ssrc[s*4+head] + sdh;
    e = (e > 0.f) ? e : 0.2f*e;
    m = fmaxf(m, e);
  }
  // pass 2: exp-sum + weighted feature gather
  float den = 0.f, a0=0.f,a1=0.f,a2=0.f,a3=0.f;
  for (int j=0;j<dg;++j){
    int s = csr_src[ro+j];
    float e = ssrc[s*4+head] + sdh;
    e = (e > 0.f) ? e : 0.2f*e;
    float ex = expf(e - m);
    den += ex;
    float4 u = *(const float4*)(h2 + (size_t)s*HIDD + lane*4);
    a0 += ex*u.x; a1 += ex*u.y; a2 += ex*u.z; a3 += ex*u.w;
  }
  float inv = 1.f/den;
  int c0 = lane*4;
  float y0 = fmaxf(a0*inv + bias[c0+0], 0.f);
  float y1 = fmaxf(a1*inv + bias[c0+1], 0.f);
  float y2 = fmaxf(a2*inv + bias[c0+2], 0.f);
  float y3 = fmaxf(a3*inv + bias[c0+3], 0.f);
  // layernorm over 256 channels (wave-wide)
  float sum = y0+y1+y2+y3;
  #pragma unroll
  for (int o=32;o>=1;o>>=1) sum += __shfl_xor(sum, o);
  float mu = sum * (1.f/256.f);
  float d0=y0-mu, d1=y1-mu, d2=y2-mu, d3=y3-mu;
  float sq = d0*d0 + d1*d1 + d2*d2 + d3*d3;
  #pragma unroll
  for (int o=32;o>=1;o>>=1) sq += __shfl_xor(sq, o);
  float rs = rsqrtf(sq*(1.f/256.f) + LN_EPSF);
  float4 o4 = make_float4(d0*rs*g[c0+0] + bb[c0+0],
                          d1*rs*g[c0+1] + bb[c0+1],
                          d2*rs*g[c0+2] + bb[c0+2],
                          d3*rs*g[c0+3] + bb[c0+3]);
  *(float4*)(hout + (size_t)n*HIDD + c0) = o4;
}

// ---------------- global mean pool (batch is sorted; run-length atomics) ----------------
__global__ __launch_bounds__(256) void k_pool(
    const float* __restrict__ h, const int* __restrict__ batch,
    float* __restrict__ pooled, float* __restrict__ cnt)
{
  int t = threadIdx.x;
  int chunk = (NN + gridDim.x - 1) / gridDim.x;
  int n0 = blockIdx.x*chunk;
  int n1 = min(n0 + chunk, NN);
  if (n0 >= n1) return;
  float acc = 0.f;
  int curb = batch[n0];
  int runStart = n0;
  for (int n=n0; n<n1; ++n){
    int b = batch[n];
    if (b != curb){
      atomicAdd(&pooled[curb*HIDD + t], acc);
      if (t == 0) atomicAdd(&cnt[curb], (float)(n - runStart));
      acc = 0.f; curb = b; runStart = n;
    }
    acc += h[(size_t)n*HIDD + t];
  }
  atomicAdd(&pooled[curb*HIDD + t], acc);
  if (t == 0) atomicAdd(&cnt[curb], (float)(n1 - runStart));
}

// ---------------- readout: gelu(pooled@W1+b1)@W2+b2 ----------------
__global__ __launch_bounds__(256) void k_readout(
    const float* __restrict__ pooled, const float* __restrict__ cnt,
    const float* __restrict__ w1, const float* __restrict__ b1,
    const float* __restrict__ w2, const float* __restrict__ b2,
    float* __restrict__ out)
{
  __shared__ float p[256], mid[256];
  int b = blockIdx.x, t = threadIdx.x;
  float c = fmaxf(cnt[b], 1.f);
  p[t] = pooled[b*HIDD + t] / c;
  __syncthreads();
  float acc = b1[t];
  for (int k=0;k<256;++k) acc += p[k]*w1[k*256+t];
  mid[t] = 0.5f*acc*(1.f + erff(acc*0.70710678118654752f));  // exact gelu
  __syncthreads();
  float acc2 = b2[t];
  for (int k=0;k<256;++k) acc2 += mid[k]*w2[k*256+t];
  out[b*HIDD + t] = acc2;
}

extern "C" void kernel_launch(void* const* d_in, const int* in_sizes, int n_in,
                              void* d_out, int out_size, void* d_ws, size_t ws_size,
                              hipStream_t stream)
{
  const float* x    = (const float*)d_in[0];
  const float* remb = (const float*)d_in[1];
  const float* ipw  = (const float*)d_in[2];
  const float* ipb  = (const float*)d_in[3];
  const float* gatw = (const float*)d_in[4];
  const float* asrc = (const float*)d_in[5];
  const float* adst = (const float*)d_in[6];
  const float* gatb = (const float*)d_in[7];
  const float* lng  = (const float*)d_in[8];
  const float* lnb  = (const float*)d_in[9];
  const float* row1 = (const float*)d_in[10];
  const float* rob1 = (const float*)d_in[11];
  const float* row2 = (const float*)d_in[12];
  const float* rob2 = (const float*)d_in[13];
  const int* ei   = (const int*)d_in[14];
  const int* batch= (const int*)d_in[15];
  const int* rid  = (const int*)d_in[16];

  char* ws = (char*)d_ws;
  // workspace layout (256B-aligned); zero region first so one memset covers it
  int*   deg  = (int*)  (ws + 0);          // 200192
  int*   cur  = (int*)  (ws + 200192);     // 200192
  float* cnt  = (float*)(ws + 400384);     // 256
  float* pool = (float*)(ws + 400640);     // 16384
  // ZERO_BYTES = 417024
  int*   row  = (int*)  (ws + 417024);     // 200192
  int*   part = (int*)  (ws + 617216);     // 1024
  int*   csr  = (int*)  (ws + 618240);     // 1800192
  float* ss   = (float*)(ws + 2418432);    // 800256
  float* sd   = (float*)(ws + 3218688);    // 800256
  float* pe   = (float*)(ws + 4018944);    // 12800000
  float* hA   = (float*)(ws + 16818944);   // 51200000
  float* hB   = (float*)(ws + 68018944);   // 51200000  (total ~119 MB)

  hipMemsetAsync(ws, 0, 417024, stream);

  k_degree <<<1758, 256, 0, stream>>>(ei, deg);
  k_scan1  <<<196, 256, 0, stream>>>(deg, row, part);
  k_scan2  <<<1, 256, 0, stream>>>(part, 196);
  k_scan3  <<<196, 256, 0, stream>>>(row, part);
  k_scatter<<<1758, 256, 0, stream>>>(ei, row, cur, csr);
  k_posenc <<<(NN*FF + 255)/256, 256, 0, stream>>>(pe);

  k_gemm_inproj<<<dim3(782,4), 256, 0, stream>>>(x, remb, rid, pe, ipw, ipb, hA);

  for (int l = 0; l < 4; ++l){
    k_gemm_layer<<<dim3(782,4), 256, 0, stream>>>(hA, gatw + (size_t)l*HIDD*HIDD, hB, NN, HIDD);
    k_scores   <<<12500, 256, 0, stream>>>(hB, asrc + l*HIDD, adst + l*HIDD, ss, sd);
    k_aggregate<<<12500, 256, 0, stream>>>(hB, ss, sd, row, deg, csr,
                                           gatb + l*HIDD, lng + l*HIDD, lnb + l*HIDD, hA);
  }

  k_pool   <<<128, 256, 0, stream>>>(hA, batch, pool, cnt);
  k_readout<<<16, 256, 0, stream>>>(pool, cnt, row1, rob1, row2, rob2, (float*)d_out);
}

// Round 3
// 774.614 us; speedup vs baseline: 1.4853x; 1.4853x over previous
//
#include <hip/hip_runtime.h>
#include <cmath>

typedef unsigned short u16;
typedef unsigned int u32;
typedef short bf16x8 __attribute__((ext_vector_type(8)));
typedef float f32x4 __attribute__((ext_vector_type(4)));

#define NN 50000      // nodes
#define MP 50048      // padded to 64
#define EE 400000     // raw edges
#define ET 450000     // edges + self loops
#define HIDD 256
#define KIN 192       // 3*F
#define LN_EPSF 1e-5f

__device__ __forceinline__ float bf2f(u16 u){ return __uint_as_float(((u32)u)<<16); }
__device__ __forceinline__ u16 f2bf(float f){
  u32 x = __float_as_uint(f);
  u32 r = x + 0x7fffu + ((x>>16)&1u);   // RNE
  return (u16)(r>>16);
}

// ---------------- CSR build ----------------
__global__ void k_degree(const int* __restrict__ ei, int* __restrict__ deg){
  int i = blockIdx.x*blockDim.x + threadIdx.x;
  if (i >= ET) return;
  int d = (i < EE) ? ei[EE + i] : (i - EE);
  atomicAdd(&deg[d], 1);
}

__global__ void k_scan1(const int* __restrict__ deg, int* __restrict__ row_off, int* __restrict__ part){
  __shared__ int s[256];
  int n = blockIdx.x*256 + threadIdx.x;
  int v = (n < NN) ? deg[n] : 0;
  s[threadIdx.x] = v;
  __syncthreads();
  for (int off=1; off<256; off<<=1){
    int t = (threadIdx.x >= off) ? s[threadIdx.x - off] : 0;
    __syncthreads();
    s[threadIdx.x] += t;
    __syncthreads();
  }
  if (n < NN) row_off[n] = s[threadIdx.x] - v;
  if (threadIdx.x == 255) part[blockIdx.x] = s[255];
}

__global__ void k_scan2(int* __restrict__ part, int nparts){
  __shared__ int s[256];
  int v = (threadIdx.x < nparts) ? part[threadIdx.x] : 0;
  s[threadIdx.x] = v;
  __syncthreads();
  for (int off=1; off<256; off<<=1){
    int t = (threadIdx.x >= off) ? s[threadIdx.x - off] : 0;
    __syncthreads();
    s[threadIdx.x] += t;
    __syncthreads();
  }
  if (threadIdx.x < nparts) part[threadIdx.x] = s[threadIdx.x] - v;
}

__global__ void k_scan3(int* __restrict__ row_off, const int* __restrict__ part){
  int n = blockIdx.x*256 + threadIdx.x;
  if (n < NN) row_off[n] += part[blockIdx.x];
}

__global__ void k_scatter(const int* __restrict__ ei, const int* __restrict__ row_off,
                          int* __restrict__ cur, int* __restrict__ csr_src){
  int i = blockIdx.x*blockDim.x + threadIdx.x;
  if (i >= ET) return;
  int s, d;
  if (i < EE){ s = ei[i]; d = ei[EE + i]; } else { s = i - EE; d = i - EE; }
  int pos = row_off[d] + atomicAdd(&cur[d], 1);
  csr_src[pos] = s;
}

// ---------------- feats = [x | remb[rid] | posenc] as bf16 [MP][192], pad rows zeroed ----------------
__global__ __launch_bounds__(256) void k_feats(
    const float* __restrict__ x, const float* __restrict__ remb,
    const int* __restrict__ rid, u16* __restrict__ feats)
{
  int e = blockIdx.x*768 + threadIdx.x;
  #pragma unroll
  for (int it=0; it<3; ++it, e+=256){
    int n = e / 192;
    int c = e - n*192;
    if (n >= MP) break;
    float v = 0.f;
    if (n < NN){
      if (c < 64){
        v = x[n*64 + c];
      } else if (c < 128){
        v = remb[rid[n]*64 + (c-64)];
      } else {
        int i = c - 128;
        float rate = exp2f(-(float)(2*(i>>1)) * (1.0f/64.0f) * 13.287712379549449f);
        float s, cc;
        sincosf((float)n * rate, &s, &cc);
        v = (i & 1) ? cc : s;
      }
    }
    feats[(size_t)n*192 + c] = f2bf(v);
  }
}

// ---------------- weight convert+transpose to bf16 Wt[N][K] ----------------
__global__ __launch_bounds__(256) void k_wt(
    const float* __restrict__ ipw, const float* __restrict__ gatw,
    u16* __restrict__ wtin, u16* __restrict__ wtl)
{
  int idx = blockIdx.x*256 + threadIdx.x;
  if (idx < 49152){               // inproj: [192][256] -> [256][192]
    int n = idx / 192, k = idx - n*192;
    wtin[idx] = f2bf(ipw[k*256 + n]);
  } else {
    int j = idx - 49152;          // gat: 4 x [256][256] -> [256][256]^T
    if (j < 262144){
      int l = j >> 16, rem = j & 65535;
      int n = rem >> 8, k = rem & 255;
      wtl[j] = f2bf(gatw[l*65536 + k*256 + n]);
    }
  }
}

// ---------------- MFMA GEMM: C[M][256](bf16) = A[M][K](bf16) @ Wt[256][K]^T (+bias) ----------------
// wave: 64x64 tile (4x4 of 16x16x32 frags); block: 64 rows x 256 cols; no LDS (Wt L2-resident)
__global__ __launch_bounds__(256) void k_gemm_mfma(
    const u16* __restrict__ A, const u16* __restrict__ Wt,
    const float* __restrict__ bias, u16* __restrict__ C, int M, int K)
{
  int wave = threadIdx.x >> 6;
  int lane = threadIdx.x & 63;
  int quad = lane >> 4;
  int lm = lane & 15;
  int r0 = blockIdx.x * 64;
  int c0 = wave * 64;
  f32x4 acc[4][4] = {};
  for (int k0 = 0; k0 < K; k0 += 32){
    bf16x8 a[4], b[4];
    #pragma unroll
    for (int i=0;i<4;++i)
      a[i] = *(const bf16x8*)(A + (size_t)(r0 + i*16 + lm)*K + k0 + quad*8);
    #pragma unroll
    for (int j=0;j<4;++j)
      b[j] = *(const bf16x8*)(Wt + (size_t)(c0 + j*16 + lm)*K + k0 + quad*8);
    #pragma unroll
    for (int i=0;i<4;++i)
      #pragma unroll
      for (int j=0;j<4;++j)
        acc[i][j] = __builtin_amdgcn_mfma_f32_16x16x32_bf16(a[i], b[j], acc[i][j], 0, 0, 0);
  }
  // C/D layout: col = lane&15, row = quad*4 + reg  [verified m89/m91]
  #pragma unroll
  for (int i=0;i<4;++i){
    #pragma unroll
    for (int r=0;r<4;++r){
      int row = r0 + i*16 + quad*4 + r;
      if (row < M){
        #pragma unroll
        for (int j=0;j<4;++j){
          int col = c0 + j*16 + lm;
          float v = acc[i][j][r];
          if (bias) v += bias[col];
          C[(size_t)row*256 + col] = f2bf(v);
        }
      }
    }
  }
}

// ---------------- per-node attention scores (wave per node) ----------------
__global__ __launch_bounds__(256) void k_scores(
    const u16* __restrict__ h2, const float* __restrict__ asrc, const float* __restrict__ adst,
    float* __restrict__ ssrc, float* __restrict__ sdst)
{
  int wv = (blockIdx.x*blockDim.x + threadIdx.x) >> 6;
  if (wv >= NN) return;
  int lane = threadIdx.x & 63;
  int c0 = lane*4;
  ushort4 hv = *(const ushort4*)(h2 + (size_t)wv*HIDD + c0);
  float h0=bf2f(hv.x), h1=bf2f(hv.y), h2v=bf2f(hv.z), h3=bf2f(hv.w);
  float ps = h0*asrc[c0] + h1*asrc[c0+1] + h2v*asrc[c0+2] + h3*asrc[c0+3];
  float pd = h0*adst[c0] + h1*adst[c0+1] + h2v*adst[c0+2] + h3*adst[c0+3];
  #pragma unroll
  for (int o=1;o<16;o<<=1){ ps += __shfl_xor(ps,o); pd += __shfl_xor(pd,o); }
  if ((lane & 15) == 0){
    int head = lane >> 4;
    ssrc[wv*4+head] = ps;
    sdst[wv*4+head] = pd;
  }
}

// ---------------- fused GAT aggregate + bias + relu + layernorm (wave per dst node) ----------------
__global__ __launch_bounds__(256) void k_aggregate(
    const u16* __restrict__ h2, const float* __restrict__ ssrc, const float* __restrict__ sdst,
    const int* __restrict__ row_off, const int* __restrict__ deg, const int* __restrict__ csr_src,
    const float* __restrict__ bias, const float* __restrict__ g, const float* __restrict__ bb,
    u16* __restrict__ hout)
{
  int n = (blockIdx.x*blockDim.x + threadIdx.x) >> 6;
  if (n >= NN) return;
  int lane = threadIdx.x & 63;
  int head = lane >> 4;
  float sdh = sdst[n*4 + head];
  int ro = row_off[n];
  int dg = deg[n];
  // pass 1: segment max of leaky_relu scores (per head)
  float m = -1e30f;
  for (int j=0;j<dg;++j){
    int s = csr_src[ro+j];
    float e = ssrc[s*4+head] + sdh;
    e = (e > 0.f) ? e : 0.2f*e;
    m = fmaxf(m, e);
  }
  // pass 2: exp-sum + weighted feature gather
  float den = 0.f, a0=0.f,a1=0.f,a2=0.f,a3=0.f;
  for (int j=0;j<dg;++j){
    int s = csr_src[ro+j];
    float e = ssrc[s*4+head] + sdh;
    e = (e > 0.f) ? e : 0.2f*e;
    float ex = expf(e - m);
    den += ex;
    ushort4 u = *(const ushort4*)(h2 + (size_t)s*HIDD + lane*4);
    a0 += ex*bf2f(u.x); a1 += ex*bf2f(u.y); a2 += ex*bf2f(u.z); a3 += ex*bf2f(u.w);
  }
  float inv = 1.f/den;
  int c0 = lane*4;
  float y0 = fmaxf(a0*inv + bias[c0+0], 0.f);
  float y1 = fmaxf(a1*inv + bias[c0+1], 0.f);
  float y2 = fmaxf(a2*inv + bias[c0+2], 0.f);
  float y3 = fmaxf(a3*inv + bias[c0+3], 0.f);
  // layernorm over 256 channels (wave-wide)
  float sum = y0+y1+y2+y3;
  #pragma unroll
  for (int o=32;o>=1;o>>=1) sum += __shfl_xor(sum, o);
  float mu = sum * (1.f/256.f);
  float d0=y0-mu, d1=y1-mu, d2=y2-mu, d3=y3-mu;
  float sq = d0*d0 + d1*d1 + d2*d2 + d3*d3;
  #pragma unroll
  for (int o=32;o>=1;o>>=1) sq += __shfl_xor(sq, o);
  float rs = rsqrtf(sq*(1.f/256.f) + LN_EPSF);
  ushort4 o4;
  o4.x = f2bf(d0*rs*g[c0+0] + bb[c0+0]);
  o4.y = f2bf(d1*rs*g[c0+1] + bb[c0+1]);
  o4.z = f2bf(d2*rs*g[c0+2] + bb[c0+2]);
  o4.w = f2bf(d3*rs*g[c0+3] + bb[c0+3]);
  *(ushort4*)(hout + (size_t)n*HIDD + c0) = o4;
}

// ---------------- global mean pool: 1024 blocks, run-length atomics (batch sorted) ----------------
__global__ __launch_bounds__(256) void k_pool(
    const u16* __restrict__ h, const int* __restrict__ batch,
    float* __restrict__ pooled, float* __restrict__ cnt)
{
  const int chunk = 49;  // 1024*49 >= NN
  int t = threadIdx.x;
  int n0 = blockIdx.x*chunk;
  int n1 = min(n0 + chunk, NN);
  if (n0 >= n1) return;
  float acc = 0.f;
  int curb = batch[n0];
  int runStart = n0;
  for (int n=n0; n<n1; ++n){
    int b = batch[n];
    if (b != curb){
      atomicAdd(&pooled[curb*HIDD + t], acc);
      if (t == 0) atomicAdd(&cnt[curb], (float)(n - runStart));
      acc = 0.f; curb = b; runStart = n;
    }
    acc += bf2f(h[(size_t)n*HIDD + t]);
  }
  atomicAdd(&pooled[curb*HIDD + t], acc);
  if (t == 0) atomicAdd(&cnt[curb], (float)(n1 - runStart));
}

// ---------------- readout: gelu(pooled@W1+b1)@W2+b2 (fp32, tiny) ----------------
__global__ __launch_bounds__(256) void k_readout(
    const float* __restrict__ pooled, const float* __restrict__ cnt,
    const float* __restrict__ w1, const float* __restrict__ b1,
    const float* __restrict__ w2, const float* __restrict__ b2,
    float* __restrict__ out)
{
  __shared__ float p[256], mid[256];
  int b = blockIdx.x, t = threadIdx.x;
  float c = fmaxf(cnt[b], 1.f);
  p[t] = pooled[b*HIDD + t] / c;
  __syncthreads();
  float acc = b1[t];
  for (int k=0;k<256;++k) acc += p[k]*w1[k*256+t];
  mid[t] = 0.5f*acc*(1.f + erff(acc*0.70710678118654752f));
  __syncthreads();
  float acc2 = b2[t];
  for (int k=0;k<256;++k) acc2 += mid[k]*w2[k*256+t];
  out[b*HIDD + t] = acc2;
}

extern "C" void kernel_launch(void* const* d_in, const int* in_sizes, int n_in,
                              void* d_out, int out_size, void* d_ws, size_t ws_size,
                              hipStream_t stream)
{
  const float* x    = (const float*)d_in[0];
  const float* remb = (const float*)d_in[1];
  const float* ipw  = (const float*)d_in[2];
  const float* ipb  = (const float*)d_in[3];
  const float* gatw = (const float*)d_in[4];
  const float* asrc = (const float*)d_in[5];
  const float* adst = (const float*)d_in[6];
  const float* gatb = (const float*)d_in[7];
  const float* lng  = (const float*)d_in[8];
  const float* lnb  = (const float*)d_in[9];
  const float* row1 = (const float*)d_in[10];
  const float* rob1 = (const float*)d_in[11];
  const float* row2 = (const float*)d_in[12];
  const float* rob2 = (const float*)d_in[13];
  const int* ei   = (const int*)d_in[14];
  const int* batch= (const int*)d_in[15];
  const int* rid  = (const int*)d_in[16];

  char* ws = (char*)d_ws;
  int*   deg  = (int*)  (ws + 0);          // 200192
  int*   cur  = (int*)  (ws + 200192);     // 200192
  float* cnt  = (float*)(ws + 400384);     // 256
  float* pool = (float*)(ws + 400640);     // 16384
  // ZERO_BYTES = 417024
  int*   row  = (int*)  (ws + 417024);     // 200192
  int*   part = (int*)  (ws + 617216);     // 1024
  int*   csr  = (int*)  (ws + 618240);     // 1800192
  float* ss   = (float*)(ws + 2418432);    // 800256
  float* sd   = (float*)(ws + 3218688);    // 800256
  u16*   feats= (u16*)  (ws + 4018944);    // 50048*192*2 = 19218432
  u16*   wtin = (u16*)  (ws + 23237376);   // 256*192*2   = 98304
  u16*   wtl  = (u16*)  (ws + 23335680);   // 4*256*256*2 = 524288
  u16*   hA   = (u16*)  (ws + 23859968);   // 50048*256*2 = 25624576
  u16*   hB   = (u16*)  (ws + 49484544);   // 25624576  (ends ~75.1 MB)

  hipMemsetAsync(ws, 0, 417024, stream);

  k_degree <<<1758, 256, 0, stream>>>(ei, deg);
  k_scan1  <<<196, 256, 0, stream>>>(deg, row, part);
  k_scan2  <<<1, 256, 0, stream>>>(part, 196);
  k_scan3  <<<196, 256, 0, stream>>>(row, part);
  k_scatter<<<1758, 256, 0, stream>>>(ei, row, cur, csr);
  k_feats  <<<12512, 256, 0, stream>>>(x, remb, rid, feats);
  k_wt     <<<1216, 256, 0, stream>>>(ipw, gatw, wtin, wtl);

  k_gemm_mfma<<<MP/64, 256, 0, stream>>>(feats, wtin, ipb, hA, NN, KIN);

  for (int l = 0; l < 4; ++l){
    k_gemm_mfma<<<MP/64, 256, 0, stream>>>(hA, wtl + (size_t)l*HIDD*HIDD, nullptr, hB, NN, HIDD);
    k_scores   <<<12500, 256, 0, stream>>>(hB, asrc + l*HIDD, adst + l*HIDD, ss, sd);
    k_aggregate<<<12500, 256, 0, stream>>>(hB, ss, sd, row, deg, csr,
                                           gatb + l*HIDD, lng + l*HIDD, lnb + l*HIDD, hA);
  }

  k_pool   <<<1024, 256, 0, stream>>>(hA, batch, pool, cnt);
  k_readout<<<16, 256, 0, stream>>>(pool, cnt, row1, rob1, row2, rob2, (float*)d_out);
}

// Round 4
// 590.605 us; speedup vs baseline: 1.9481x; 1.3116x over previous
//
#include <hip/hip_runtime.h>
#include <cmath>

typedef unsigned short u16;
typedef unsigned int u32;
typedef short bf16x8 __attribute__((ext_vector_type(8)));
typedef float f32x4 __attribute__((ext_vector_type(4)));

#define NN 50000      // nodes
#define MP 50048      // padded to 64
#define EE 400000     // raw edges
#define ET 450000     // edges + self loops
#define HIDD 256
#define KIN 192       // 3*F
#define LN_EPSF 1e-5f

__device__ __forceinline__ float bf2f(u16 u){ return __uint_as_float(((u32)u)<<16); }
__device__ __forceinline__ u16 f2bf(float f){
  u32 x = __float_as_uint(f);
  u32 r = x + 0x7fffu + ((x>>16)&1u);   // RNE
  return (u16)(r>>16);
}

// ---------------- CSR build ----------------
__global__ void k_degree(const int* __restrict__ ei, int* __restrict__ deg){
  int i = blockIdx.x*blockDim.x + threadIdx.x;
  if (i >= ET) return;
  int d = (i < EE) ? ei[EE + i] : (i - EE);
  atomicAdd(&deg[d], 1);
}

__global__ void k_scan1(const int* __restrict__ deg, int* __restrict__ row_off, int* __restrict__ part){
  __shared__ int s[256];
  int n = blockIdx.x*256 + threadIdx.x;
  int v = (n < NN) ? deg[n] : 0;
  s[threadIdx.x] = v;
  __syncthreads();
  for (int off=1; off<256; off<<=1){
    int t = (threadIdx.x >= off) ? s[threadIdx.x - off] : 0;
    __syncthreads();
    s[threadIdx.x] += t;
    __syncthreads();
  }
  if (n < NN) row_off[n] = s[threadIdx.x] - v;
  if (threadIdx.x == 255) part[blockIdx.x] = s[255];
}

__global__ void k_scan2(int* __restrict__ part, int nparts){
  __shared__ int s[256];
  int v = (threadIdx.x < nparts) ? part[threadIdx.x] : 0;
  s[threadIdx.x] = v;
  __syncthreads();
  for (int off=1; off<256; off<<=1){
    int t = (threadIdx.x >= off) ? s[threadIdx.x - off] : 0;
    __syncthreads();
    s[threadIdx.x] += t;
    __syncthreads();
  }
  if (threadIdx.x < nparts) part[threadIdx.x] = s[threadIdx.x] - v;
}

__global__ void k_scan3(int* __restrict__ row_off, const int* __restrict__ part){
  int n = blockIdx.x*256 + threadIdx.x;
  if (n < NN) row_off[n] += part[blockIdx.x];
}

__global__ void k_scatter(const int* __restrict__ ei, const int* __restrict__ row_off,
                          int* __restrict__ cur, int* __restrict__ csr_src){
  int i = blockIdx.x*blockDim.x + threadIdx.x;
  if (i >= ET) return;
  int s, d;
  if (i < EE){ s = ei[i]; d = ei[EE + i]; } else { s = i - EE; d = i - EE; }
  int pos = row_off[d] + atomicAdd(&cur[d], 1);
  csr_src[pos] = s;
}

// ---------------- feats = [x | remb[rid] | posenc] as bf16 [MP][192], pad rows zeroed ----------------
__global__ __launch_bounds__(256) void k_feats(
    const float* __restrict__ x, const float* __restrict__ remb,
    const int* __restrict__ rid, u16* __restrict__ feats)
{
  int e = blockIdx.x*768 + threadIdx.x;
  #pragma unroll
  for (int it=0; it<3; ++it, e+=256){
    int n = e / 192;
    int c = e - n*192;
    if (n >= MP) break;
    float v = 0.f;
    if (n < NN){
      if (c < 64){
        v = x[n*64 + c];
      } else if (c < 128){
        v = remb[rid[n]*64 + (c-64)];
      } else {
        int i = c - 128;
        float rate = exp2f(-(float)(2*(i>>1)) * (1.0f/64.0f) * 13.287712379549449f);
        float s, cc;
        sincosf((float)n * rate, &s, &cc);
        v = (i & 1) ? cc : s;
      }
    }
    feats[(size_t)n*192 + c] = f2bf(v);
  }
}

// ---------------- weight convert+transpose to bf16 Wt[N][K] ----------------
__global__ __launch_bounds__(256) void k_wt(
    const float* __restrict__ ipw, const float* __restrict__ gatw,
    u16* __restrict__ wtin, u16* __restrict__ wtl)
{
  int idx = blockIdx.x*256 + threadIdx.x;
  if (idx < 49152){               // inproj: [192][256] -> [256][192]
    int n = idx / 192, k = idx - n*192;
    wtin[idx] = f2bf(ipw[k*256 + n]);
  } else {
    int j = idx - 49152;          // gat: 4 x [256][256] -> [256][256]^T
    if (j < 262144){
      int l = j >> 16, rem = j & 65535;
      int n = rem >> 8, k = rem & 255;
      wtl[j] = f2bf(gatw[l*65536 + k*256 + n]);
    }
  }
}

// ---------------- MFMA GEMM + fused per-head attention scores ----------------
// C[M][256](bf16) = A[M][K](bf16) @ Wt[256][K]^T (+bias).
// wave: 64x64 tile = one head's 64 cols; scores reduced in-register via shuffles.
__global__ __launch_bounds__(256) void k_gemm_mfma(
    const u16* __restrict__ A, const u16* __restrict__ Wt,
    const float* __restrict__ bias,
    const float* __restrict__ asrc, const float* __restrict__ adst,
    float* __restrict__ ssrc, float* __restrict__ sdst,
    u16* __restrict__ C, int M, int K)
{
  int wave = threadIdx.x >> 6;
  int lane = threadIdx.x & 63;
  int quad = lane >> 4;
  int lm = lane & 15;
  int r0 = blockIdx.x * 64;
  int c0 = wave * 64;
  f32x4 acc[4][4] = {};
  for (int k0 = 0; k0 < K; k0 += 32){
    bf16x8 a[4], b[4];
    #pragma unroll
    for (int i=0;i<4;++i)
      a[i] = *(const bf16x8*)(A + (size_t)(r0 + i*16 + lm)*K + k0 + quad*8);
    #pragma unroll
    for (int j=0;j<4;++j)
      b[j] = *(const bf16x8*)(Wt + (size_t)(c0 + j*16 + lm)*K + k0 + quad*8);
    #pragma unroll
    for (int i=0;i<4;++i)
      #pragma unroll
      for (int j=0;j<4;++j)
        acc[i][j] = __builtin_amdgcn_mfma_f32_16x16x32_bf16(a[i], b[j], acc[i][j], 0, 0, 0);
  }
  float av[4], dv[4];
  if (asrc){
    #pragma unroll
    for (int j=0;j<4;++j){ av[j] = asrc[c0 + j*16 + lm]; dv[j] = adst[c0 + j*16 + lm]; }
  }
  // C/D layout: col = lane&15, row = quad*4 + reg  [verified m89/m91]
  #pragma unroll
  for (int i=0;i<4;++i){
    #pragma unroll
    for (int r=0;r<4;++r){
      int row = r0 + i*16 + quad*4 + r;
      if (row < M){
        #pragma unroll
        for (int j=0;j<4;++j){
          int col = c0 + j*16 + lm;
          float v = acc[i][j][r];
          if (bias) v += bias[col];
          C[(size_t)row*256 + col] = f2bf(v);
        }
      }
      if (asrc){
        float ps = 0.f, pd = 0.f;
        #pragma unroll
        for (int j=0;j<4;++j){ ps += acc[i][j][r]*av[j]; pd += acc[i][j][r]*dv[j]; }
        #pragma unroll
        for (int o=1;o<16;o<<=1){ ps += __shfl_xor(ps,o); pd += __shfl_xor(pd,o); }
        if (lm == 0 && row < M){
          ssrc[row*4 + wave] = ps;
          sdst[row*4 + wave] = pd;
        }
      }
    }
  }
}

// ---------------- fused GAT aggregate + bias + relu + layernorm (wave per dst node) ----------------
// single pass (no segment-max: |e| <~ 3 by construction), dual gather chains for MLP
__global__ __launch_bounds__(256) void k_aggregate(
    const u16* __restrict__ h2, const float* __restrict__ ssrc, const float* __restrict__ sdst,
    const int* __restrict__ row_off, const int* __restrict__ deg, const int* __restrict__ csr_src,
    const float* __restrict__ bias, const float* __restrict__ g, const float* __restrict__ bb,
    u16* __restrict__ hout)
{
  int n = __builtin_amdgcn_readfirstlane((blockIdx.x*blockDim.x + threadIdx.x) >> 6);
  if (n >= NN) return;
  int lane = threadIdx.x & 63;
  int head = lane >> 4;
  float sdh = sdst[n*4 + head];
  int ro = __builtin_amdgcn_readfirstlane(row_off[n]);
  int dg = __builtin_amdgcn_readfirstlane(deg[n]);
  float denA = 0.f, a0=0.f,a1=0.f,a2=0.f,a3=0.f;
  float denB = 0.f, b0=0.f,b1=0.f,b2=0.f,b3=0.f;
  int loff = lane*4;
  int j = 0;
  for (; j + 2 <= dg; j += 2){
    int sA = __builtin_amdgcn_readfirstlane(csr_src[ro+j]);
    int sB = __builtin_amdgcn_readfirstlane(csr_src[ro+j+1]);
    ushort4 uA = *(const ushort4*)(h2 + (size_t)sA*HIDD + loff);
    ushort4 uB = *(const ushort4*)(h2 + (size_t)sB*HIDD + loff);
    float eA = ssrc[sA*4+head] + sdh;
    float eB = ssrc[sB*4+head] + sdh;
    eA = (eA > 0.f) ? eA : 0.2f*eA;
    eB = (eB > 0.f) ? eB : 0.2f*eB;
    float xA = __expf(eA), xB = __expf(eB);
    denA += xA; denB += xB;
    a0 += xA*bf2f(uA.x); a1 += xA*bf2f(uA.y); a2 += xA*bf2f(uA.z); a3 += xA*bf2f(uA.w);
    b0 += xB*bf2f(uB.x); b1 += xB*bf2f(uB.y); b2 += xB*bf2f(uB.z); b3 += xB*bf2f(uB.w);
  }
  if (j < dg){
    int sA = __builtin_amdgcn_readfirstlane(csr_src[ro+j]);
    ushort4 uA = *(const ushort4*)(h2 + (size_t)sA*HIDD + loff);
    float eA = ssrc[sA*4+head] + sdh;
    eA = (eA > 0.f) ? eA : 0.2f*eA;
    float xA = __expf(eA);
    denA += xA;
    a0 += xA*bf2f(uA.x); a1 += xA*bf2f(uA.y); a2 += xA*bf2f(uA.z); a3 += xA*bf2f(uA.w);
  }
  float inv = 1.f / (denA + denB);
  a0 += b0; a1 += b1; a2 += b2; a3 += b3;
  int c0 = loff;
  float y0 = fmaxf(a0*inv + bias[c0+0], 0.f);
  float y1 = fmaxf(a1*inv + bias[c0+1], 0.f);
  float y2 = fmaxf(a2*inv + bias[c0+2], 0.f);
  float y3 = fmaxf(a3*inv + bias[c0+3], 0.f);
  // layernorm over 256 channels (wave-wide)
  float sum = y0+y1+y2+y3;
  #pragma unroll
  for (int o=32;o>=1;o>>=1) sum += __shfl_xor(sum, o);
  float mu = sum * (1.f/256.f);
  float d0=y0-mu, d1=y1-mu, d2=y2-mu, d3=y3-mu;
  float sq = d0*d0 + d1*d1 + d2*d2 + d3*d3;
  #pragma unroll
  for (int o=32;o>=1;o>>=1) sq += __shfl_xor(sq, o);
  float rs = rsqrtf(sq*(1.f/256.f) + LN_EPSF);
  ushort4 o4;
  o4.x = f2bf(d0*rs*g[c0+0] + bb[c0+0]);
  o4.y = f2bf(d1*rs*g[c0+1] + bb[c0+1]);
  o4.z = f2bf(d2*rs*g[c0+2] + bb[c0+2]);
  o4.w = f2bf(d3*rs*g[c0+3] + bb[c0+3]);
  *(ushort4*)(hout + (size_t)n*HIDD + c0) = o4;
}

// ---------------- global mean pool: 1024 blocks, run-length atomics (batch sorted) ----------------
__global__ __launch_bounds__(256) void k_pool(
    const u16* __restrict__ h, const int* __restrict__ batch,
    float* __restrict__ pooled, float* __restrict__ cnt)
{
  const int chunk = 49;  // 1024*49 >= NN
  int t = threadIdx.x;
  int n0 = blockIdx.x*chunk;
  int n1 = min(n0 + chunk, NN);
  if (n0 >= n1) return;
  float acc = 0.f;
  int curb = batch[n0];
  int runStart = n0;
  for (int n=n0; n<n1; ++n){
    int b = batch[n];
    if (b != curb){
      atomicAdd(&pooled[curb*HIDD + t], acc);
      if (t == 0) atomicAdd(&cnt[curb], (float)(n - runStart));
      acc = 0.f; curb = b; runStart = n;
    }
    acc += bf2f(h[(size_t)n*HIDD + t]);
  }
  atomicAdd(&pooled[curb*HIDD + t], acc);
  if (t == 0) atomicAdd(&cnt[curb], (float)(n1 - runStart));
}

// ---------------- readout: gelu(pooled@W1+b1)@W2+b2 (fp32, tiny) ----------------
__global__ __launch_bounds__(256) void k_readout(
    const float* __restrict__ pooled, const float* __restrict__ cnt,
    const float* __restrict__ w1, const float* __restrict__ b1,
    const float* __restrict__ w2, const float* __restrict__ b2,
    float* __restrict__ out)
{
  __shared__ float p[256], mid[256];
  int b = blockIdx.x, t = threadIdx.x;
  float c = fmaxf(cnt[b], 1.f);
  p[t] = pooled[b*HIDD + t] / c;
  __syncthreads();
  float acc = b1[t];
  for (int k=0;k<256;++k) acc += p[k]*w1[k*256+t];
  mid[t] = 0.5f*acc*(1.f + erff(acc*0.70710678118654752f));
  __syncthreads();
  float acc2 = b2[t];
  for (int k=0;k<256;++k) acc2 += mid[k]*w2[k*256+t];
  out[b*HIDD + t] = acc2;
}

extern "C" void kernel_launch(void* const* d_in, const int* in_sizes, int n_in,
                              void* d_out, int out_size, void* d_ws, size_t ws_size,
                              hipStream_t stream)
{
  const float* x    = (const float*)d_in[0];
  const float* remb = (const float*)d_in[1];
  const float* ipw  = (const float*)d_in[2];
  const float* ipb  = (const float*)d_in[3];
  const float* gatw = (const float*)d_in[4];
  const float* asrc = (const float*)d_in[5];
  const float* adst = (const float*)d_in[6];
  const float* gatb = (const float*)d_in[7];
  const float* lng  = (const float*)d_in[8];
  const float* lnb  = (const float*)d_in[9];
  const float* row1 = (const float*)d_in[10];
  const float* rob1 = (const float*)d_in[11];
  const float* row2 = (const float*)d_in[12];
  const float* rob2 = (const float*)d_in[13];
  const int* ei   = (const int*)d_in[14];
  const int* batch= (const int*)d_in[15];
  const int* rid  = (const int*)d_in[16];

  char* ws = (char*)d_ws;
  int*   deg  = (int*)  (ws + 0);          // 200192
  int*   cur  = (int*)  (ws + 200192);     // 200192
  float* cnt  = (float*)(ws + 400384);     // 256
  float* pool = (float*)(ws + 400640);     // 16384
  // ZERO_BYTES = 417024
  int*   row  = (int*)  (ws + 417024);     // 200192
  int*   part = (int*)  (ws + 617216);     // 1024
  int*   csr  = (int*)  (ws + 618240);     // 1800192
  float* ss   = (float*)(ws + 2418432);    // 800768 (MP*4 floats)
  float* sd   = (float*)(ws + 3219200);    // 800768
  u16*   feats= (u16*)  (ws + 4019968);    // 50048*192*2 = 19218432
  u16*   wtin = (u16*)  (ws + 23238400);   // 256*192*2   = 98304
  u16*   wtl  = (u16*)  (ws + 23336704);   // 4*256*256*2 = 524288
  u16*   hA   = (u16*)  (ws + 23860992);   // 50048*256*2 = 25624576
  u16*   hB   = (u16*)  (ws + 49485568);   // 25624576  (ends ~75.1 MB)

  hipMemsetAsync(ws, 0, 417024, stream);

  k_degree <<<1758, 256, 0, stream>>>(ei, deg);
  k_scan1  <<<196, 256, 0, stream>>>(deg, row, part);
  k_scan2  <<<1, 256, 0, stream>>>(part, 196);
  k_scan3  <<<196, 256, 0, stream>>>(row, part);
  k_scatter<<<1758, 256, 0, stream>>>(ei, row, cur, csr);
  k_feats  <<<12512, 256, 0, stream>>>(x, remb, rid, feats);
  k_wt     <<<1216, 256, 0, stream>>>(ipw, gatw, wtin, wtl);

  // input projection (bias, no scores)
  k_gemm_mfma<<<MP/64, 256, 0, stream>>>(feats, wtin, ipb, nullptr, nullptr,
                                         nullptr, nullptr, hA, NN, KIN);

  for (int l = 0; l < 4; ++l){
    // layer GEMM (no bias, fused scores for this layer's attention vectors)
    k_gemm_mfma<<<MP/64, 256, 0, stream>>>(hA, wtl + (size_t)l*HIDD*HIDD, nullptr,
                                           asrc + l*HIDD, adst + l*HIDD, ss, sd,
                                           hB, NN, HIDD);
    k_aggregate<<<12500, 256, 0, stream>>>(hB, ss, sd, row, deg, csr,
                                           gatb + l*HIDD, lng + l*HIDD, lnb + l*HIDD, hA);
  }

  k_pool   <<<1024, 256, 0, stream>>>(hA, batch, pool, cnt);
  k_readout<<<16, 256, 0, stream>>>(pool, cnt, row1, rob1, row2, rob2, (float*)d_out);
}

// Round 5
// 546.433 us; speedup vs baseline: 2.1056x; 1.0808x over previous
//
#include <hip/hip_runtime.h>
#include <cmath>

typedef unsigned short u16;
typedef unsigned int u32;
typedef short bf16x8 __attribute__((ext_vector_type(8)));
typedef float f32x4 __attribute__((ext_vector_type(4)));

#define NN 50000      // nodes
#define MP 50048      // padded to 64
#define EE 400000     // raw edges
#define ET 450000     // edges + self loops
#define HIDD 256
#define KIN 192       // 3*F
#define LN_EPSF 1e-5f

__device__ __forceinline__ float bf2f(u16 u){ return __uint_as_float(((u32)u)<<16); }
__device__ __forceinline__ u16 f2bf(float f){
  u32 x = __float_as_uint(f);
  u32 r = x + 0x7fffu + ((x>>16)&1u);   // RNE
  return (u16)(r>>16);
}

__device__ __forceinline__ void dma16(const u16* g, u16* lds){
  __builtin_amdgcn_global_load_lds(
      (const __attribute__((address_space(1))) void*)g,
      (__attribute__((address_space(3))) void*)lds, 16, 0, 0);
}

// ---------------- CSR build ----------------
__global__ void k_degree(const int* __restrict__ ei, int* __restrict__ deg){
  int i = blockIdx.x*blockDim.x + threadIdx.x;
  if (i >= ET) return;
  int d = (i < EE) ? ei[EE + i] : (i - EE);
  atomicAdd(&deg[d], 1);
}

__global__ void k_scan1(const int* __restrict__ deg, int* __restrict__ row_off, int* __restrict__ part){
  __shared__ int s[256];
  int n = blockIdx.x*256 + threadIdx.x;
  int v = (n < NN) ? deg[n] : 0;
  s[threadIdx.x] = v;
  __syncthreads();
  for (int off=1; off<256; off<<=1){
    int t = (threadIdx.x >= off) ? s[threadIdx.x - off] : 0;
    __syncthreads();
    s[threadIdx.x] += t;
    __syncthreads();
  }
  if (n < NN) row_off[n] = s[threadIdx.x] - v;
  if (threadIdx.x == 255) part[blockIdx.x] = s[255];
}

__global__ void k_scan2(int* __restrict__ part, int nparts){
  __shared__ int s[256];
  int v = (threadIdx.x < nparts) ? part[threadIdx.x] : 0;
  s[threadIdx.x] = v;
  __syncthreads();
  for (int off=1; off<256; off<<=1){
    int t = (threadIdx.x >= off) ? s[threadIdx.x - off] : 0;
    __syncthreads();
    s[threadIdx.x] += t;
    __syncthreads();
  }
  if (threadIdx.x < nparts) part[threadIdx.x] = s[threadIdx.x] - v;
}

__global__ void k_scan3(int* __restrict__ row_off, const int* __restrict__ part){
  int n = blockIdx.x*256 + threadIdx.x;
  if (n < NN) row_off[n] += part[blockIdx.x];
}

__global__ void k_scatter(const int* __restrict__ ei, const int* __restrict__ row_off,
                          int* __restrict__ cur, int* __restrict__ csr_src){
  int i = blockIdx.x*blockDim.x + threadIdx.x;
  if (i >= ET) return;
  int s, d;
  if (i < EE){ s = ei[i]; d = ei[EE + i]; } else { s = i - EE; d = i - EE; }
  int pos = row_off[d] + atomicAdd(&cur[d], 1);
  csr_src[pos] = s;
}

// ---------------- feats = [x | remb[rid] | posenc] as bf16 [MP][192], pad rows zeroed ----------------
__global__ __launch_bounds__(256) void k_feats(
    const float* __restrict__ x, const float* __restrict__ remb,
    const int* __restrict__ rid, u16* __restrict__ feats)
{
  int e = blockIdx.x*768 + threadIdx.x;
  #pragma unroll
  for (int it=0; it<3; ++it, e+=256){
    int n = e / 192;
    int c = e - n*192;
    if (n >= MP) break;
    float v = 0.f;
    if (n < NN){
      if (c < 64){
        v = x[n*64 + c];
      } else if (c < 128){
        v = remb[rid[n]*64 + (c-64)];
      } else {
        int i = c - 128;
        float rate = exp2f(-(float)(2*(i>>1)) * (1.0f/64.0f) * 13.287712379549449f);
        float s, cc;
        sincosf((float)n * rate, &s, &cc);
        v = (i & 1) ? cc : s;
      }
    }
    feats[(size_t)n*192 + c] = f2bf(v);
  }
}

// ---------------- weight convert+transpose to bf16 Wt[N][K] ----------------
__global__ __launch_bounds__(256) void k_wt(
    const float* __restrict__ ipw, const float* __restrict__ gatw,
    u16* __restrict__ wtin, u16* __restrict__ wtl)
{
  int idx = blockIdx.x*256 + threadIdx.x;
  if (idx < 49152){               // inproj: [192][256] -> [256][192]
    int n = idx / 192, k = idx - n*192;
    wtin[idx] = f2bf(ipw[k*256 + n]);
  } else {
    int j = idx - 49152;          // gat: 4 x [256][256] -> [256][256]^T
    if (j < 262144){
      int l = j >> 16, rem = j & 65535;
      int n = rem >> 8, k = rem & 255;
      wtl[j] = f2bf(gatw[l*65536 + k*256 + n]);
    }
  }
}

// ---------------- MFMA GEMM + fused per-head attention scores ----------------
// C[M][256](bf16) = A[M][K](bf16) @ Wt[256][K]^T (+bias).
// A-tile (64 rows x K) staged ONCE per block in LDS via global_load_lds (coalesced,
// XOR-swizzled chunks -> conflict-free ds_read_b128). One barrier per block.
// wave: 64x64 tile = one head's 64 cols; scores reduced in-register via shuffles.
template<int K>
__global__ __launch_bounds__(256) void k_gemm_mfma(
    const u16* __restrict__ A, const u16* __restrict__ Wt,
    const float* __restrict__ bias,
    const float* __restrict__ asrc, const float* __restrict__ adst,
    float* __restrict__ ssrc, float* __restrict__ sdst,
    u16* __restrict__ C, int M)
{
  constexpr int CPR = K/8;            // 16B chunks per row
  __shared__ u16 As[64*K];            // 64 rows x K bf16 (24KB or 32KB)
  int wave = threadIdx.x >> 6;
  int lane = threadIdx.x & 63;
  int quad = lane >> 4;
  int lm = lane & 15;
  int r0 = blockIdx.x * 64;
  int c0 = wave * 64;

  // stage A-tile: CPR wave-instrs of 64 lanes x 16B; instr m covers LDS slots [m*64, m*64+64)
  // slot(r,p) = r*CPR + p holds global chunk j = p ^ (r&7)
  for (int m = wave; m < CPR; m += 4){
    int s = m*64 + lane;
    int r = s / CPR;
    int p = s - r*CPR;
    int j = p ^ (r & 7);
    dma16(A + (size_t)(r0 + r)*K + j*8, As + (size_t)m*64*8);
  }
  __syncthreads();

  f32x4 acc[4][4] = {};
  for (int ks = 0; ks < K/32; ++ks){
    bf16x8 a[4], b[4];
    #pragma unroll
    for (int j=0;j<4;++j)
      b[j] = *(const bf16x8*)(Wt + (size_t)(c0 + j*16 + lm)*K + ks*32 + quad*8);
    #pragma unroll
    for (int i=0;i<4;++i){
      int slot = (i*16 + lm)*CPR + ((ks*4 + quad) ^ (lm & 7));
      a[i] = *(const bf16x8*)(As + (size_t)slot*8);
    }
    #pragma unroll
    for (int i=0;i<4;++i)
      #pragma unroll
      for (int j=0;j<4;++j)
        acc[i][j] = __builtin_amdgcn_mfma_f32_16x16x32_bf16(a[i], b[j], acc[i][j], 0, 0, 0);
  }

  float av[4], dv[4];
  if (asrc){
    #pragma unroll
    for (int j=0;j<4;++j){ av[j] = asrc[c0 + j*16 + lm]; dv[j] = adst[c0 + j*16 + lm]; }
  }
  // C/D layout: col = lane&15, row = quad*4 + reg  [verified m89/m91]
  #pragma unroll
  for (int i=0;i<4;++i){
    #pragma unroll
    for (int r=0;r<4;++r){
      int row = r0 + i*16 + quad*4 + r;
      if (row < M){
        #pragma unroll
        for (int j=0;j<4;++j){
          int col = c0 + j*16 + lm;
          float v = acc[i][j][r];
          if (bias) v += bias[col];
          C[(size_t)row*256 + col] = f2bf(v);
        }
      }
      if (asrc){
        float ps = 0.f, pd = 0.f;
        #pragma unroll
        for (int j=0;j<4;++j){ ps += acc[i][j][r]*av[j]; pd += acc[i][j][r]*dv[j]; }
        #pragma unroll
        for (int o=1;o<16;o<<=1){ ps += __shfl_xor(ps,o); pd += __shfl_xor(pd,o); }
        if (lm == 0 && row < M){
          ssrc[row*4 + wave] = ps;
          sdst[row*4 + wave] = pd;
        }
      }
    }
  }
}

// ---------------- fused GAT aggregate + bias + relu + layernorm (wave per dst node) ----------------
// single pass (no segment-max: |e| <~ 3 by construction), dual gather chains for MLP
__global__ __launch_bounds__(256) void k_aggregate(
    const u16* __restrict__ h2, const float* __restrict__ ssrc, const float* __restrict__ sdst,
    const int* __restrict__ row_off, const int* __restrict__ deg, const int* __restrict__ csr_src,
    const float* __restrict__ bias, const float* __restrict__ g, const float* __restrict__ bb,
    u16* __restrict__ hout)
{
  int n = __builtin_amdgcn_readfirstlane((blockIdx.x*blockDim.x + threadIdx.x) >> 6);
  if (n >= NN) return;
  int lane = threadIdx.x & 63;
  int head = lane >> 4;
  float sdh = sdst[n*4 + head];
  int ro = __builtin_amdgcn_readfirstlane(row_off[n]);
  int dg = __builtin_amdgcn_readfirstlane(deg[n]);
  float denA = 0.f, a0=0.f,a1=0.f,a2=0.f,a3=0.f;
  float denB = 0.f, b0=0.f,b1=0.f,b2=0.f,b3=0.f;
  int loff = lane*4;
  int j = 0;
  for (; j + 2 <= dg; j += 2){
    int sA = __builtin_amdgcn_readfirstlane(csr_src[ro+j]);
    int sB = __builtin_amdgcn_readfirstlane(csr_src[ro+j+1]);
    ushort4 uA = *(const ushort4*)(h2 + (size_t)sA*HIDD + loff);
    ushort4 uB = *(const ushort4*)(h2 + (size_t)sB*HIDD + loff);
    float eA = ssrc[sA*4+head] + sdh;
    float eB = ssrc[sB*4+head] + sdh;
    eA = (eA > 0.f) ? eA : 0.2f*eA;
    eB = (eB > 0.f) ? eB : 0.2f*eB;
    float xA = __expf(eA), xB = __expf(eB);
    denA += xA; denB += xB;
    a0 += xA*bf2f(uA.x); a1 += xA*bf2f(uA.y); a2 += xA*bf2f(uA.z); a3 += xA*bf2f(uA.w);
    b0 += xB*bf2f(uB.x); b1 += xB*bf2f(uB.y); b2 += xB*bf2f(uB.z); b3 += xB*bf2f(uB.w);
  }
  if (j < dg){
    int sA = __builtin_amdgcn_readfirstlane(csr_src[ro+j]);
    ushort4 uA = *(const ushort4*)(h2 + (size_t)sA*HIDD + loff);
    float eA = ssrc[sA*4+head] + sdh;
    eA = (eA > 0.f) ? eA : 0.2f*eA;
    float xA = __expf(eA);
    denA += xA;
    a0 += xA*bf2f(uA.x); a1 += xA*bf2f(uA.y); a2 += xA*bf2f(uA.z); a3 += xA*bf2f(uA.w);
  }
  float inv = 1.f / (denA + denB);
  a0 += b0; a1 += b1; a2 += b2; a3 += b3;
  int c0 = loff;
  float y0 = fmaxf(a0*inv + bias[c0+0], 0.f);
  float y1 = fmaxf(a1*inv + bias[c0+1], 0.f);
  float y2 = fmaxf(a2*inv + bias[c0+2], 0.f);
  float y3 = fmaxf(a3*inv + bias[c0+3], 0.f);
  // layernorm over 256 channels (wave-wide)
  float sum = y0+y1+y2+y3;
  #pragma unroll
  for (int o=32;o>=1;o>>=1) sum += __shfl_xor(sum, o);
  float mu = sum * (1.f/256.f);
  float d0=y0-mu, d1=y1-mu, d2=y2-mu, d3=y3-mu;
  float sq = d0*d0 + d1*d1 + d2*d2 + d3*d3;
  #pragma unroll
  for (int o=32;o>=1;o>>=1) sq += __shfl_xor(sq, o);
  float rs = rsqrtf(sq*(1.f/256.f) + LN_EPSF);
  ushort4 o4;
  o4.x = f2bf(d0*rs*g[c0+0] + bb[c0+0]);
  o4.y = f2bf(d1*rs*g[c0+1] + bb[c0+1]);
  o4.z = f2bf(d2*rs*g[c0+2] + bb[c0+2]);
  o4.w = f2bf(d3*rs*g[c0+3] + bb[c0+3]);
  *(ushort4*)(hout + (size_t)n*HIDD + c0) = o4;
}

// ---------------- global mean pool: 1024 blocks, run-length atomics (batch sorted) ----------------
__global__ __launch_bounds__(256) void k_pool(
    const u16* __restrict__ h, const int* __restrict__ batch,
    float* __restrict__ pooled, float* __restrict__ cnt)
{
  const int chunk = 49;  // 1024*49 >= NN
  int t = threadIdx.x;
  int n0 = blockIdx.x*chunk;
  int n1 = min(n0 + chunk, NN);
  if (n0 >= n1) return;
  float acc = 0.f;
  int curb = batch[n0];
  int runStart = n0;
  for (int n=n0; n<n1; ++n){
    int b = batch[n];
    if (b != curb){
      atomicAdd(&pooled[curb*HIDD + t], acc);
      if (t == 0) atomicAdd(&cnt[curb], (float)(n - runStart));
      acc = 0.f; curb = b; runStart = n;
    }
    acc += bf2f(h[(size_t)n*HIDD + t]);
  }
  atomicAdd(&pooled[curb*HIDD + t], acc);
  if (t == 0) atomicAdd(&cnt[curb], (float)(n1 - runStart));
}

// ---------------- readout: gelu(pooled@W1+b1)@W2+b2 (fp32, tiny) ----------------
__global__ __launch_bounds__(256) void k_readout(
    const float* __restrict__ pooled, const float* __restrict__ cnt,
    const float* __restrict__ w1, const float* __restrict__ b1,
    const float* __restrict__ w2, const float* __restrict__ b2,
    float* __restrict__ out)
{
  __shared__ float p[256], mid[256];
  int b = blockIdx.x, t = threadIdx.x;
  float c = fmaxf(cnt[b], 1.f);
  p[t] = pooled[b*HIDD + t] / c;
  __syncthreads();
  float acc = b1[t];
  for (int k=0;k<256;++k) acc += p[k]*w1[k*256+t];
  mid[t] = 0.5f*acc*(1.f + erff(acc*0.70710678118654752f));
  __syncthreads();
  float acc2 = b2[t];
  for (int k=0;k<256;++k) acc2 += mid[k]*w2[k*256+t];
  out[b*HIDD + t] = acc2;
}

extern "C" void kernel_launch(void* const* d_in, const int* in_sizes, int n_in,
                              void* d_out, int out_size, void* d_ws, size_t ws_size,
                              hipStream_t stream)
{
  const float* x    = (const float*)d_in[0];
  const float* remb = (const float*)d_in[1];
  const float* ipw  = (const float*)d_in[2];
  const float* ipb  = (const float*)d_in[3];
  const float* gatw = (const float*)d_in[4];
  const float* asrc = (const float*)d_in[5];
  const float* adst = (const float*)d_in[6];
  const float* gatb = (const float*)d_in[7];
  const float* lng  = (const float*)d_in[8];
  const float* lnb  = (const float*)d_in[9];
  const float* row1 = (const float*)d_in[10];
  const float* rob1 = (const float*)d_in[11];
  const float* row2 = (const float*)d_in[12];
  const float* rob2 = (const float*)d_in[13];
  const int* ei   = (const int*)d_in[14];
  const int* batch= (const int*)d_in[15];
  const int* rid  = (const int*)d_in[16];

  char* ws = (char*)d_ws;
  int*   deg  = (int*)  (ws + 0);          // 200192
  int*   cur  = (int*)  (ws + 200192);     // 200192
  float* cnt  = (float*)(ws + 400384);     // 256
  float* pool = (float*)(ws + 400640);     // 16384
  // ZERO_BYTES = 417024
  int*   row  = (int*)  (ws + 417024);     // 200192
  int*   part = (int*)  (ws + 617216);     // 1024
  int*   csr  = (int*)  (ws + 618240);     // 1800192
  float* ss   = (float*)(ws + 2418432);    // 800768 (MP*4 floats)
  float* sd   = (float*)(ws + 3219200);    // 800768
  u16*   feats= (u16*)  (ws + 4019968);    // 50048*192*2 = 19218432
  u16*   wtin = (u16*)  (ws + 23238400);   // 256*192*2   = 98304
  u16*   wtl  = (u16*)  (ws + 23336704);   // 4*256*256*2 = 524288
  u16*   hA   = (u16*)  (ws + 23860992);   // 50048*256*2 = 25624576
  u16*   hB   = (u16*)  (ws + 49485568);   // 25624576  (ends ~75.1 MB)

  hipMemsetAsync(ws, 0, 417024, stream);

  k_degree <<<1758, 256, 0, stream>>>(ei, deg);
  k_scan1  <<<196, 256, 0, stream>>>(deg, row, part);
  k_scan2  <<<1, 256, 0, stream>>>(part, 196);
  k_scan3  <<<196, 256, 0, stream>>>(row, part);
  k_scatter<<<1758, 256, 0, stream>>>(ei, row, cur, csr);
  k_feats  <<<12512, 256, 0, stream>>>(x, remb, rid, feats);
  k_wt     <<<1216, 256, 0, stream>>>(ipw, gatw, wtin, wtl);

  // input projection (bias, no scores)
  k_gemm_mfma<KIN><<<MP/64, 256, 0, stream>>>(feats, wtin, ipb, nullptr, nullptr,
                                              nullptr, nullptr, hA, NN);

  for (int l = 0; l < 4; ++l){
    // layer GEMM (no bias, fused scores for this layer's attention vectors)
    k_gemm_mfma<HIDD><<<MP/64, 256, 0, stream>>>(hA, wtl + (size_t)l*HIDD*HIDD, nullptr,
                                                 asrc + l*HIDD, adst + l*HIDD, ss, sd,
                                                 hB, NN);
    k_aggregate<<<12500, 256, 0, stream>>>(hB, ss, sd, row, deg, csr,
                                           gatb + l*HIDD, lng + l*HIDD, lnb + l*HIDD, hA);
  }

  k_pool   <<<1024, 256, 0, stream>>>(hA, batch, pool, cnt);
  k_readout<<<16, 256, 0, stream>>>(pool, cnt, row1, rob1, row2, rob2, (float*)d_out);
}